// Round 21
// baseline (384.490 us; speedup 1.0000x reference)
//
#include <hip/hip_runtime.h>
#include <hip/hip_bf16.h>
#include <cstdint>
#include <cstddef>

#define B_   4
#define T_   4096
#define C_   1024
#define H_   16
#define NC_  64
#define M_   (B_*T_)     // 16384 rows
#define N3_  (3*C_)      // 3072
#define NT32 32          // K=1024 / BK=32

typedef __attribute__((ext_vector_type(4))) float  f32x4;
typedef __attribute__((ext_vector_type(8))) __bf16 bf16x8;
typedef __attribute__((ext_vector_type(4))) __bf16 bf16x4;
typedef __attribute__((ext_vector_type(8))) unsigned short u16x8;

__device__ __forceinline__ void glds16(void* lds, const void* g) {
  __builtin_amdgcn_global_load_lds((const __attribute__((address_space(1))) void*)g,
                                   (__attribute__((address_space(3))) void*)lds,
                                   16, 0, 0);
}
#define MFMA_BF16 __builtin_amdgcn_mfma_f32_16x16x32_bf16

// chunk-kernel LDS slot swizzle (r19, proven): [64][LDW=72], phys slot = s ^ (row>>3 & 7)
#define LDW 72
__device__ __forceinline__ int sw_off(int row, int s) {
  return row * LDW + ((s ^ ((row >> 3) & 7)) << 3);
}

// ---------------- fp32 -> bf16 ----------------
__global__ __launch_bounds__(256) void cvt_f32_bf16(const float* __restrict__ in,
                                                    __bf16* __restrict__ out, int n4) {
  int i = blockIdx.x * 256 + threadIdx.x;
  if (i >= n4) return;
  float4 v = reinterpret_cast<const float4*>(in)[i];
  bf16x4 o;
  o[0] = (__bf16)v.x; o[1] = (__bf16)v.y; o[2] = (__bf16)v.z; o[3] = (__bf16)v.w;
  reinterpret_cast<bf16x4*>(out)[i] = o;
}

// ---------------- RoPE cos/sin table ----------------
__global__ __launch_bounds__(256) void rope_tab(float2* __restrict__ tab) {
  int gid = blockIdx.x * 256 + threadIdx.x;  // 131072 entries
  int t = gid >> 5, dp = gid & 31;
  float invf = exp2f(-(float)dp * (13.287712379549449f / 32.0f));
  float ang = (float)t * invf;
  float s, c;
  sincosf(ang, &s, &c);
  tab[gid] = make_float2(c, s);
}

// ============ 256x128 GEMM, BK=32, superrow LDS (128B lines, 8-slot XOR),   ============
// ============ 4 waves 2Mx2N each 128x64 (0.375 reads/MFMA), 48KB LDS ->     ============
// ============ 3 blocks/CU, 2-barrier tile loop, counted vmcnt(6), XCD swz.  ============
// FUSE==1: bf16 out + rope/relu on q,k col-blocks (bn<16).  FUSE==2: fp32 out.
// grid: NBN*64 blocks, 256 threads. K fixed 1024.
template<int FUSE, int NBN>
__global__ __launch_bounds__(256) void gemm_s32(const __bf16* __restrict__ A,
                                                const __bf16* __restrict__ Bt,
                                                void* __restrict__ Cout,
                                                const float2* __restrict__ tab,
                                                int N) {
  __shared__ __bf16 sA[2][256 * 32];   // 16KB per buf: 128 superrows x 128B
  __shared__ __bf16 sB[2][128 * 32];   //  8KB per buf:  64 superrows x 128B
  const int tid  = threadIdx.x;
  const int lane = tid & 63;
  const int wave = tid >> 6;
  const int wm = wave >> 1, wn = wave & 1;   // 2M x 2N, wave tile 128x64
  const int nwg = NBN * 64, cpx = nwg / 8;
  const int wgid = (int)blockIdx.x;
  const int swzid = (wgid % 8) * cpx + wgid / 8;
  const int bn = swzid % NBN, bm = swzid / NBN;
  const int fr = lane & 15, kq = lane >> 4;
  const int K = C_;

  // superrow staging: per issue 256 thr x 16B = 4KB = 32 superrows (64 rows).
  // thread t: local superrow = t>>3, phys slot = t&7; inverse-swizzled logical
  // slot ss = (t&7)^((t>>3)&7) -> src row = 2*(t>>3)+(ss>>2), src k = (ss&3)*8.
  const int ssl = (tid & 7) ^ ((tid >> 3) & 7);
  const int rloc = 2 * (tid >> 3) + (ssl >> 2);   // 0..63 within issue
  const int kloc = (ssl & 3) * 8;
  const __bf16* Ag = A  + (size_t)(bm * 256 + rloc) * K + kloc;
  const __bf16* Bg = Bt + (size_t)(bn * 128 + rloc) * K + kloc;

  f32x4 acc[8][4];
#pragma unroll
  for (int i = 0; i < 8; i++)
#pragma unroll
    for (int j = 0; j < 4; j++) acc[i][j] = (f32x4)0.0f;

  // prologue: stage tile 0 (A: 4 issues of 64 rows; B: 2 issues)
#pragma unroll
  for (int q = 0; q < 4; ++q)
    glds16((char*)sA[0] + q * 4096 + tid * 16, Ag + (size_t)q * 64 * K);
#pragma unroll
  for (int q = 0; q < 2; ++q)
    glds16((char*)sB[0] + q * 4096 + tid * 16, Bg + (size_t)q * 64 * K);
  asm volatile("s_waitcnt vmcnt(0)" ::: "memory");
  __builtin_amdgcn_sched_barrier(0);
  __builtin_amdgcn_s_barrier();

  bf16x8 af[8], bfr[4];
  for (int t = 0; t < NT32; ++t) {
    const int d = t & 1, nb = d ^ 1;
    const bool dostage = (t + 1 < NT32);
    const int kb1 = (t + 1) * 32;
    const char* Ab = (const char*)sA[d];
    const char* Bb = (const char*)sB[d];

    // stage tile t+1 (6 issues), then counted wait: 6 outstanding => tile t done
    if (dostage) {
#pragma unroll
      for (int q = 0; q < 4; ++q)
        glds16((char*)sA[nb] + q * 4096 + tid * 16, Ag + (size_t)q * 64 * K + kb1);
#pragma unroll
      for (int q = 0; q < 2; ++q)
        glds16((char*)sB[nb] + q * 4096 + tid * 16, Bg + (size_t)q * 64 * K + kb1);
      asm volatile("s_waitcnt vmcnt(6)" ::: "memory");
    } else {
      asm volatile("s_waitcnt vmcnt(0)" ::: "memory");
    }
    __builtin_amdgcn_sched_barrier(0);
    __builtin_amdgcn_s_barrier();

    // 12 frag reads: addr = superrow*128 + ((l ^ (sr&7))*16), l = (row&1)*4+kq
#pragma unroll
    for (int i = 0; i < 8; ++i) {
      int row = wm * 128 + i * 16 + fr;
      int sr = row >> 1;
      af[i] = *(const bf16x8*)(Ab + sr * 128 + ((((row & 1) << 2) | kq) ^ (sr & 7)) * 16);
    }
#pragma unroll
    for (int j = 0; j < 4; ++j) {
      int row = wn * 64 + j * 16 + fr;
      int sr = row >> 1;
      bfr[j] = *(const bf16x8*)(Bb + sr * 128 + ((((row & 1) << 2) | kq) ^ (sr & 7)) * 16);
    }
    asm volatile("s_waitcnt lgkmcnt(0)" ::: "memory");
    __builtin_amdgcn_sched_barrier(0);
    __builtin_amdgcn_s_setprio(1);
#pragma unroll
    for (int i = 0; i < 8; ++i)
#pragma unroll
      for (int j = 0; j < 4; ++j)
        acc[i][j] = MFMA_BF16(af[i], bfr[j], acc[i][j], 0, 0, 0);
    __builtin_amdgcn_s_setprio(0);
    __builtin_amdgcn_s_barrier();   // seals buffer d before t+1 restages it
  }

  // epilogue: D layout col=fr, row=kq*4+reg
  const int rg4 = kq * 4;
  const int cb = bn * 128 + wn * 64;
  if (FUSE == 1 && bn < 16) {
#pragma unroll
    for (int i = 0; i < 8; ++i)
#pragma unroll
      for (int r = 0; r < 4; ++r) {
        size_t row = (size_t)bm * 256 + wm * 128 + i * 16 + rg4 + r;
        int tt = (int)(row & (T_ - 1));
#pragma unroll
        for (int j = 0; j < 2; ++j) {
          int dp = j * 16 + fr;
          float2 cs = tab[tt * 32 + dp];
          float x1 = acc[i][j][r], x2 = acc[i][j + 2][r];
          float o1 = fmaxf(x1 * cs.x - x2 * cs.y, 0.0f);
          float o2 = fmaxf(x2 * cs.x + x1 * cs.y, 0.0f);
          ((__bf16*)Cout)[row * N + cb + j * 16 + fr]      = (__bf16)o1;
          ((__bf16*)Cout)[row * N + cb + j * 16 + fr + 32] = (__bf16)o2;
        }
      }
  } else {
#pragma unroll
    for (int i = 0; i < 8; ++i)
#pragma unroll
      for (int j = 0; j < 4; ++j) {
        size_t row = (size_t)bm * 256 + wm * 128 + i * 16 + rg4;
        size_t col = (size_t)cb + j * 16 + fr;
#pragma unroll
        for (int r = 0; r < 4; ++r) {
          if (FUSE == 2) ((float*)Cout)[(row + r) * N + col]  = acc[i][j][r];
          else           ((__bf16*)Cout)[(row + r) * N + col] = (__bf16)acc[i][j][r];
        }
      }
  }
}

// ---------------- stage A: G_c = K_c^T V_c per (b,h,chunk); swizzled LDS (r19) ----------------
__global__ __launch_bounds__(256) void chunk_kv(const __bf16* __restrict__ qkv,
                                                __bf16* __restrict__ G) {
  __shared__ __bf16 Kt[64 * LDW];
  __shared__ __bf16 Vt[64 * LDW];
  const int bid = blockIdx.x;
  const int c = bid & (NC_ - 1);
  const int bh = bid >> 6;
  const int h = bh & (H_ - 1);
  const int b = bh >> 4;
  const int tid = threadIdx.x;
  const size_t row0 = (size_t)b * T_ + c * 64;
  const int kcol = C_ + h * 64;
  const int vcol = 2 * C_ + h * 64;
#pragma unroll
  for (int it = 0; it < 2; ++it) {
    int task = tid + it * 256;
    int t = task >> 3;
    int d0 = (task & 7) * 8;
    const size_t rb = (row0 + t) * N3_;
    u16x8 kv = *(const u16x8*)(qkv + rb + kcol + d0);
    u16x8 vv = *(const u16x8*)(qkv + rb + vcol + d0);
    const int ts = t >> 3, tl = t & 7;
#pragma unroll
    for (int j = 0; j < 8; j++) {
      int d = d0 + j;
      ((unsigned short*)Kt)[sw_off(d, ts) + tl] = kv[j];
      ((unsigned short*)Vt)[sw_off(d, ts) + tl] = vv[j];
    }
  }
  __syncthreads();
  const int lane = tid & 63, wave = tid >> 6;
  const int gr = (wave >> 1) * 32, gc = (wave & 1) * 32;
  const int fr = lane & 15, kq = lane >> 4;
  f32x4 acc[2][2];
#pragma unroll
  for (int i = 0; i < 2; i++)
#pragma unroll
    for (int j = 0; j < 2; j++) acc[i][j] = (f32x4)0.0f;
#pragma unroll
  for (int kk = 0; kk < 2; ++kk) {
    bf16x8 af[2], bfr[2];
#pragma unroll
    for (int i = 0; i < 2; i++) {
      int row = gr + i * 16 + fr;
      af[i] = *(const bf16x8*)(Kt + sw_off(row, kk * 4 + kq));
    }
#pragma unroll
    for (int j = 0; j < 2; j++) {
      int row = gc + j * 16 + fr;
      bfr[j] = *(const bf16x8*)(Vt + sw_off(row, kk * 4 + kq));
    }
#pragma unroll
    for (int i = 0; i < 2; i++)
#pragma unroll
      for (int j = 0; j < 2; j++)
        acc[i][j] = MFMA_BF16(af[i], bfr[j], acc[i][j], 0, 0, 0);
  }
  const int rg = kq * 4;
  __bf16* Gb = G + (size_t)bid * 4096;
#pragma unroll
  for (int i = 0; i < 2; i++)
#pragma unroll
    for (int j = 0; j < 2; j++)
#pragma unroll
      for (int r = 0; r < 4; r++)
        Gb[(gr + i * 16 + rg + r) * 64 + gc + j * 16 + fr] = (__bf16)acc[i][j][r];
}

// ---------------- stage B: prefix over chunks ----------------
__global__ __launch_bounds__(256) void prefix_scan(const __bf16* __restrict__ G,
                                                   const float* __restrict__ sigma0,
                                                   __bf16* __restrict__ S,
                                                   float* __restrict__ sigma_out,
                                                   const float* __restrict__ eta) {
  const int blk = blockIdx.x;       // 0..255
  const int bh = blk >> 2;
  const int dq = blk & 3;
  const int tid = threadIdx.x;
  const int d = dq * 16 + (tid >> 4);
  const int e0 = (tid & 15) * 4;
  const float eta_s = eta[0];
  const size_t base_de = (size_t)d * 64 + e0;
  float acc[4], s0[4];
#pragma unroll
  for (int j = 0; j < 4; j++) {
    acc[j] = 0.0f;
    s0[j] = sigma0[(size_t)bh * 4096 + base_de + j];
  }
  for (int c = 0; c < NC_; ++c) {
    const size_t off = ((size_t)bh * NC_ + c) * 4096 + base_de;
    bf16x4 sv;
#pragma unroll
    for (int j = 0; j < 4; j++) sv[j] = (__bf16)(s0[j] + eta_s * acc[j]);
    *(bf16x4*)(S + off) = sv;
    bf16x4 g = *(const bf16x4*)(G + off);
#pragma unroll
    for (int j = 0; j < 4; j++) acc[j] += (float)g[j];
  }
  float4 v;
  v.x = s0[0] + eta_s * acc[0];
  v.y = s0[1] + eta_s * acc[1];
  v.z = s0[2] + eta_s * acc[2];
  v.w = s0[3] + eta_s * acc[3];
  *reinterpret_cast<float4*>(sigma_out + (size_t)bh * 4096 + base_de) = v;
}

// ---------------- stage C: O = eta*strict_tril(Q K^T) V + Q S_c; swizzled LDS (r19) ----------------
__global__ __launch_bounds__(256) void chunk_out(const __bf16* __restrict__ qkv,
                                                 const __bf16* __restrict__ S,
                                                 __bf16* __restrict__ outp,
                                                 const float* __restrict__ eta) {
  __shared__ __bf16 Qs[64 * LDW];
  __shared__ __bf16 Ks[64 * LDW];
  __shared__ __bf16 Vt[64 * LDW];
  __shared__ __bf16 St[64 * LDW];
  __shared__ __bf16 Ps[64 * LDW];
  const int bid = blockIdx.x;
  const int c = bid & 63, bh = bid >> 6, h = bh & 15, b = bh >> 4;
  const int tid = threadIdx.x;
  const size_t row0 = (size_t)b * T_ + c * 64;
  const float eta_s = eta[0];
#pragma unroll
  for (int it = 0; it < 2; ++it) {
    int task = tid + it * 256;
    int t = task >> 3, d0 = (task & 7) * 8;
    const size_t rb = (row0 + t) * N3_;
    const int ds = d0 >> 3, ts = t >> 3, tl = t & 7;
    *(u16x8*)(Qs + sw_off(t, ds)) = *(const u16x8*)(qkv + rb + h * 64 + d0);
    *(u16x8*)(Ks + sw_off(t, ds)) = *(const u16x8*)(qkv + rb + C_ + h * 64 + d0);
    u16x8 vv = *(const u16x8*)(qkv + rb + 2 * C_ + h * 64 + d0);
    u16x8 sv = *(const u16x8*)(S + (size_t)bid * 4096 + t * 64 + d0);
#pragma unroll
    for (int j = 0; j < 8; j++) {
      int e = d0 + j;
      ((unsigned short*)Vt)[sw_off(e, ts) + tl] = vv[j];
      ((unsigned short*)St)[sw_off(e, ts) + tl] = sv[j];
    }
  }
  __syncthreads();
  const int lane = tid & 63, wave = tid >> 6;
  const int qr = (wave >> 1) * 32, qc = (wave & 1) * 32;
  const int fr = lane & 15, kq = lane >> 4, rg = (lane >> 4) * 4;
  {
    f32x4 pacc[2][2];
#pragma unroll
    for (int i = 0; i < 2; i++)
#pragma unroll
      for (int j = 0; j < 2; j++) pacc[i][j] = (f32x4)0.0f;
#pragma unroll
    for (int kk = 0; kk < 2; ++kk) {
      bf16x8 af[2], bfr[2];
#pragma unroll
      for (int i = 0; i < 2; i++) {
        int row = qr + i * 16 + fr;
        af[i] = *(const bf16x8*)(Qs + sw_off(row, kk * 4 + kq));
      }
#pragma unroll
      for (int j = 0; j < 2; j++) {
        int row = qc + j * 16 + fr;
        bfr[j] = *(const bf16x8*)(Ks + sw_off(row, kk * 4 + kq));
      }
#pragma unroll
      for (int i = 0; i < 2; i++)
#pragma unroll
        for (int j = 0; j < 2; j++)
          pacc[i][j] = MFMA_BF16(af[i], bfr[j], pacc[i][j], 0, 0, 0);
    }
#pragma unroll
    for (int i = 0; i < 2; i++)
#pragma unroll
      for (int j = 0; j < 2; j++)
#pragma unroll
        for (int r = 0; r < 4; r++) {
          int trow = qr + i * 16 + rg + r;
          int scol = qc + j * 16 + fr;
          float v = (scol < trow) ? eta_s * pacc[i][j][r] : 0.0f;
          Ps[sw_off(trow, scol >> 3) + (scol & 7)] = (__bf16)v;
        }
  }
  __syncthreads();
  {
    f32x4 oacc[2][2];
#pragma unroll
    for (int i = 0; i < 2; i++)
#pragma unroll
      for (int j = 0; j < 2; j++) oacc[i][j] = (f32x4)0.0f;
#pragma unroll
    for (int kk = 0; kk < 2; ++kk) {
      bf16x8 pa[2], vb[2], qa[2], sb[2];
#pragma unroll
      for (int i = 0; i < 2; i++) {
        int row = qr + i * 16 + fr;
        pa[i] = *(const bf16x8*)(Ps + sw_off(row, kk * 4 + kq));
        qa[i] = *(const bf16x8*)(Qs + sw_off(row, kk * 4 + kq));
      }
#pragma unroll
      for (int j = 0; j < 2; j++) {
        int row = qc + j * 16 + fr;
        vb[j] = *(const bf16x8*)(Vt + sw_off(row, kk * 4 + kq));
        sb[j] = *(const bf16x8*)(St + sw_off(row, kk * 4 + kq));
      }
#pragma unroll
      for (int i = 0; i < 2; i++)
#pragma unroll
        for (int j = 0; j < 2; j++) {
          oacc[i][j] = MFMA_BF16(pa[i], vb[j], oacc[i][j], 0, 0, 0);
          oacc[i][j] = MFMA_BF16(qa[i], sb[j], oacc[i][j], 0, 0, 0);
        }
    }
#pragma unroll
    for (int i = 0; i < 2; i++)
#pragma unroll
      for (int j = 0; j < 2; j++)
#pragma unroll
        for (int r = 0; r < 4; r++) {
          size_t row = row0 + qr + i * 16 + rg + r;
          int col = h * 64 + qc + j * 16 + fr;
          outp[row * C_ + col] = (__bf16)oacc[i][j][r];
        }
  }
}

extern "C" void kernel_launch(void* const* d_in, const int* in_sizes, int n_in,
                              void* d_out, int out_size, void* d_ws, size_t ws_size,
                              hipStream_t stream) {
  const float* x      = (const float*)d_in[0];
  const float* sigma0 = (const float*)d_in[1];
  const float* w_qkv  = (const float*)d_in[2];
  const float* w_proj = (const float*)d_in[3];
  const float* eta    = (const float*)d_in[4];
  float* out       = (float*)d_out;
  float* sigma_out = out + (size_t)M_ * C_;

  char* ws = (char*)d_ws;
  __bf16* xbf     = (__bf16*)(ws);               // 32 MB (reused as out_pre)
  __bf16* wqkvbf  = (__bf16*)(ws + 33554432);
  __bf16* wprojbf = (__bf16*)(ws + 39845888);
  __bf16* qkvbf   = (__bf16*)(ws + 41943040);    // 96 MB
  __bf16* Gws     = (__bf16*)(ws + 142606336);   // 32 MB
  __bf16* Sws     = (__bf16*)(ws + 176160768);   // 32 MB
  float2* tab     = (float2*)(ws + 176160768);   // 1 MB, dead before prefix_scan writes S

  rope_tab<<<512, 256, 0, stream>>>(tab);
  cvt_f32_bf16<<<16384, 256, 0, stream>>>(x, xbf, 4194304);
  cvt_f32_bf16<<<3072, 256, 0, stream>>>(w_qkv, wqkvbf, 786432);
  cvt_f32_bf16<<<1024, 256, 0, stream>>>(w_proj, wprojbf, 262144);
  gemm_s32<1, 24><<<1536, 256, 0, stream>>>(xbf, wqkvbf, (void*)qkvbf, tab, N3_);
  chunk_kv<<<4096, 256, 0, stream>>>(qkvbf, Gws);
  prefix_scan<<<256, 256, 0, stream>>>(Gws, sigma0, Sws, sigma_out, eta);
  chunk_out<<<4096, 256, 0, stream>>>(qkvbf, Sws, xbf, eta);
  gemm_s32<2, 8><<<512, 256, 0, stream>>>(xbf, wprojbf, (void*)out, nullptr, C_);
}

// Round 24
// 262.974 us; speedup vs baseline: 1.4621x; 1.4621x over previous
//
#include <hip/hip_runtime.h>
#include <hip/hip_bf16.h>
#include <cstdint>
#include <cstddef>

#define B_   4
#define T_   4096
#define C_   1024
#define H_   16
#define NC_  64
#define M_   (B_*T_)     // 16384 rows
#define N3_  (3*C_)      // 3072
#define NTK  16          // K=1024 / BK=64

typedef __attribute__((ext_vector_type(4))) float  f32x4;
typedef __attribute__((ext_vector_type(8))) __bf16 bf16x8;
typedef __attribute__((ext_vector_type(4))) __bf16 bf16x4;
typedef __attribute__((ext_vector_type(8))) unsigned short u16x8;

__device__ __forceinline__ void glds16(void* lds, const void* g) {
  __builtin_amdgcn_global_load_lds((const __attribute__((address_space(1))) void*)g,
                                   (__attribute__((address_space(3))) void*)lds,
                                   16, 0, 0);
}
#define MFMA_BF16 __builtin_amdgcn_mfma_f32_16x16x32_bf16

// LDS slot swizzle for 64x64 tiles stored in [64][LDW=72] (8 data slots of 8 elems + pad):
// physical slot = logical slot XOR (row>>3 & 7). Kills the 16-way transposed-store conflicts.
#define LDW 72
__device__ __forceinline__ int sw_off(int row, int s) {
  return row * LDW + ((s ^ ((row >> 3) & 7)) << 3);
}

// ---------------- fp32 -> bf16 ----------------
__global__ __launch_bounds__(256) void cvt_f32_bf16(const float* __restrict__ in,
                                                    __bf16* __restrict__ out, int n4) {
  int i = blockIdx.x * 256 + threadIdx.x;
  if (i >= n4) return;
  float4 v = reinterpret_cast<const float4*>(in)[i];
  bf16x4 o;
  o[0] = (__bf16)v.x; o[1] = (__bf16)v.y; o[2] = (__bf16)v.z; o[3] = (__bf16)v.w;
  reinterpret_cast<bf16x4*>(out)[i] = o;
}

// ---------------- RoPE cos/sin table ----------------
__global__ __launch_bounds__(256) void rope_tab(float2* __restrict__ tab) {
  int gid = blockIdx.x * 256 + threadIdx.x;  // 131072 entries
  int t = gid >> 5, dp = gid & 31;
  float invf = exp2f(-(float)dp * (13.287712379549449f / 32.0f));
  float ang = (float)t * invf;
  float s, c;
  sincosf(ang, &s, &c);
  tab[gid] = make_float2(c, s);
}

// ============ 256x256 GEMM, BK=64, 8-phase, deep prefetch, XCD swizzle (r16) ============
template<int FUSE, int NBN>
__global__ __launch_bounds__(512) void gemm_8ph(const __bf16* __restrict__ A,
                                                const __bf16* __restrict__ Bt,
                                                void* __restrict__ Cout,
                                                const float2* __restrict__ tab,
                                                int N) {
  __shared__ __bf16 sA[2][2][128 * 64];   // [dbuf][half][row 128][k 64], 16KB each
  __shared__ __bf16 sB[2][2][128 * 64];
  const int tid  = threadIdx.x;
  const int lane = tid & 63;
  const int wave = tid >> 6;
  const int wm = wave >> 2, wn = wave & 3;
  const int nwg = NBN * 64, cpx = nwg / 8;
  const int wgid = (int)blockIdx.x;
  const int swzid = (wgid % 8) * cpx + wgid / 8;
  const int bn = swzid % NBN, bm = swzid / NBN;
  const int fr = lane & 15, kq = lane >> 4;
  const int fr7 = fr & 7;
  const int K = C_;

  const int r_loc = tid >> 3;
  const int sslot = (tid & 7) ^ (r_loc & 7);
  const __bf16* Ag = A  + (size_t)(bm * 256 + r_loc) * K + sslot * 8;
  const __bf16* Bg = Bt + (size_t)(bn * 256 + r_loc) * K + sslot * 8;
  const __bf16* AgH[2] = { Ag, Ag + (size_t)128 * K };
  const __bf16* BgH[2] = { Bg, Bg + (size_t)128 * K };

  f32x4 acc[8][4];
#pragma unroll
  for (int i = 0; i < 8; i++)
#pragma unroll
    for (int j = 0; j < 4; j++) acc[i][j] = (f32x4)0.0f;

#pragma unroll
  for (int h = 0; h < 2; ++h) {
    glds16((char*)sA[0][h] +    0 + tid * 16, AgH[h]);
    glds16((char*)sA[0][h] + 8192 + tid * 16, AgH[h] + (size_t)64 * K);
    glds16((char*)sB[0][h] +    0 + tid * 16, BgH[h]);
    glds16((char*)sB[0][h] + 8192 + tid * 16, BgH[h] + (size_t)64 * K);
  }

  bf16x8 af[4][2], bfr[4][2];
  const int bloc = (wn & 1) * 64;

  for (int t = 0; t < NTK; ++t) {
    const int d = t & 1, nb = d ^ 1;
    const bool dostage = (t + 1 < NTK);
    const int kb1 = (t + 1) * 64;
    const char* Abh = (const char*)sA[d][wm];
    const char* Bbh = (const char*)sB[d][wn >> 1];

    if (dostage) {
      glds16((char*)sA[nb][0] +    0 + tid * 16, AgH[0] + kb1);
      glds16((char*)sA[nb][0] + 8192 + tid * 16, AgH[0] + (size_t)64 * K + kb1);
      glds16((char*)sA[nb][1] +    0 + tid * 16, AgH[1] + kb1);
      glds16((char*)sA[nb][1] + 8192 + tid * 16, AgH[1] + (size_t)64 * K + kb1);
      asm volatile("s_waitcnt vmcnt(4)" ::: "memory");
    } else {
      asm volatile("s_waitcnt vmcnt(0)" ::: "memory");
    }
    __builtin_amdgcn_sched_barrier(0);
    __builtin_amdgcn_s_barrier();
#pragma unroll
    for (int i = 0; i < 4; ++i)
#pragma unroll
      for (int kk = 0; kk < 2; ++kk)
        af[i][kk] = *(const bf16x8*)(Abh + (i * 16 + fr) * 128 + (((kk << 2) | kq) ^ fr7) * 16);
#pragma unroll
    for (int j = 0; j < 2; ++j)
#pragma unroll
      for (int kk = 0; kk < 2; ++kk)
        bfr[j][kk] = *(const bf16x8*)(Bbh + (bloc + j * 16 + fr) * 128 + (((kk << 2) | kq) ^ fr7) * 16);
    asm volatile("s_waitcnt lgkmcnt(0)" ::: "memory");
    __builtin_amdgcn_sched_barrier(0);
    __builtin_amdgcn_s_setprio(1);
#pragma unroll
    for (int i = 0; i < 4; ++i)
#pragma unroll
      for (int j = 0; j < 2; ++j) {
        acc[i][j] = MFMA_BF16(af[i][0], bfr[j][0], acc[i][j], 0, 0, 0);
        acc[i][j] = MFMA_BF16(af[i][1], bfr[j][1], acc[i][j], 0, 0, 0);
      }
    __builtin_amdgcn_s_setprio(0);
    __builtin_amdgcn_s_barrier();

#pragma unroll
    for (int j = 0; j < 2; ++j)
#pragma unroll
      for (int kk = 0; kk < 2; ++kk)
        bfr[j + 2][kk] = *(const bf16x8*)(Bbh + (bloc + (j + 2) * 16 + fr) * 128 + (((kk << 2) | kq) ^ fr7) * 16);
    if (dostage) {
      glds16((char*)sB[nb][0] +    0 + tid * 16, BgH[0] + kb1);
      glds16((char*)sB[nb][0] + 8192 + tid * 16, BgH[0] + (size_t)64 * K + kb1);
      glds16((char*)sB[nb][1] +    0 + tid * 16, BgH[1] + kb1);
      glds16((char*)sB[nb][1] + 8192 + tid * 16, BgH[1] + (size_t)64 * K + kb1);
    }
    __builtin_amdgcn_s_barrier();
    asm volatile("s_waitcnt lgkmcnt(0)" ::: "memory");
    __builtin_amdgcn_sched_barrier(0);
    __builtin_amdgcn_s_setprio(1);
#pragma unroll
    for (int i = 0; i < 4; ++i)
#pragma unroll
      for (int j = 0; j < 2; ++j) {
        acc[i][j + 2] = MFMA_BF16(af[i][0], bfr[j + 2][0], acc[i][j + 2], 0, 0, 0);
        acc[i][j + 2] = MFMA_BF16(af[i][1], bfr[j + 2][1], acc[i][j + 2], 0, 0, 0);
      }
    __builtin_amdgcn_s_setprio(0);
    __builtin_amdgcn_s_barrier();

#pragma unroll
    for (int i = 0; i < 4; ++i)
#pragma unroll
      for (int kk = 0; kk < 2; ++kk)
        af[i][kk] = *(const bf16x8*)(Abh + (64 + i * 16 + fr) * 128 + (((kk << 2) | kq) ^ fr7) * 16);
    asm volatile("s_waitcnt lgkmcnt(0)" ::: "memory");
    __builtin_amdgcn_sched_barrier(0);
    __builtin_amdgcn_s_setprio(1);
#pragma unroll
    for (int i = 0; i < 4; ++i)
#pragma unroll
      for (int j = 0; j < 2; ++j) {
        acc[i + 4][j] = MFMA_BF16(af[i][0], bfr[j][0], acc[i + 4][j], 0, 0, 0);
        acc[i + 4][j] = MFMA_BF16(af[i][1], bfr[j][1], acc[i + 4][j], 0, 0, 0);
      }
    __builtin_amdgcn_s_setprio(0);

    __builtin_amdgcn_s_setprio(1);
#pragma unroll
    for (int i = 0; i < 4; ++i)
#pragma unroll
      for (int j = 0; j < 2; ++j) {
        acc[i + 4][j + 2] = MFMA_BF16(af[i][0], bfr[j + 2][0], acc[i + 4][j + 2], 0, 0, 0);
        acc[i + 4][j + 2] = MFMA_BF16(af[i][1], bfr[j + 2][1], acc[i + 4][j + 2], 0, 0, 0);
      }
    __builtin_amdgcn_s_setprio(0);
    __builtin_amdgcn_s_barrier();
  }

  const int rg4 = kq * 4;
  const int cb = bn * 256 + wn * 64;
  if (FUSE == 1 && bn < 8) {
#pragma unroll
    for (int i = 0; i < 8; ++i)
#pragma unroll
      for (int r = 0; r < 4; ++r) {
        size_t row = (size_t)bm * 256 + wm * 128 + i * 16 + rg4 + r;
        int tt = (int)(row & (T_ - 1));
#pragma unroll
        for (int j = 0; j < 2; ++j) {
          int dp = j * 16 + fr;
          float2 cs = tab[tt * 32 + dp];
          float x1 = acc[i][j][r], x2 = acc[i][j + 2][r];
          float o1 = fmaxf(x1 * cs.x - x2 * cs.y, 0.0f);
          float o2 = fmaxf(x2 * cs.x + x1 * cs.y, 0.0f);
          ((__bf16*)Cout)[row * N + cb + j * 16 + fr]      = (__bf16)o1;
          ((__bf16*)Cout)[row * N + cb + j * 16 + fr + 32] = (__bf16)o2;
        }
      }
  } else {
#pragma unroll
    for (int i = 0; i < 8; ++i)
#pragma unroll
      for (int j = 0; j < 4; ++j) {
        size_t row = (size_t)bm * 256 + wm * 128 + i * 16 + rg4;
        size_t col = (size_t)cb + j * 16 + fr;
#pragma unroll
        for (int r = 0; r < 4; ++r) {
          if (FUSE == 2) ((float*)Cout)[(row + r) * N + col]  = acc[i][j][r];
          else           ((__bf16*)Cout)[(row + r) * N + col] = (__bf16)acc[i][j][r];
        }
      }
  }
}

// ---------------- stage A: G_c = K_c^T V_c per (b,h,chunk); swizzled LDS ----------------
__global__ __launch_bounds__(256) void chunk_kv(const __bf16* __restrict__ qkv,
                                                __bf16* __restrict__ G) {
  __shared__ __bf16 Kt[64 * LDW];  // Kt[d][t], slot-swizzled
  __shared__ __bf16 Vt[64 * LDW];  // Vt[e][t], slot-swizzled
  const int bid = blockIdx.x;
  const int c = bid & (NC_ - 1);
  const int bh = bid >> 6;
  const int h = bh & (H_ - 1);
  const int b = bh >> 4;
  const int tid = threadIdx.x;
  const size_t row0 = (size_t)b * T_ + c * 64;
  const int kcol = C_ + h * 64;
  const int vcol = 2 * C_ + h * 64;
#pragma unroll
  for (int it = 0; it < 2; ++it) {
    int task = tid + it * 256;
    int t = task >> 3;
    int d0 = (task & 7) * 8;
    const size_t rb = (row0 + t) * N3_;
    u16x8 kv = *(const u16x8*)(qkv + rb + kcol + d0);
    u16x8 vv = *(const u16x8*)(qkv + rb + vcol + d0);
    const int ts = t >> 3, tl = t & 7;
#pragma unroll
    for (int j = 0; j < 8; j++) {
      int d = d0 + j;
      ((unsigned short*)Kt)[sw_off(d, ts) + tl] = kv[j];
      ((unsigned short*)Vt)[sw_off(d, ts) + tl] = vv[j];
    }
  }
  __syncthreads();
  const int lane = tid & 63, wave = tid >> 6;
  const int gr = (wave >> 1) * 32, gc = (wave & 1) * 32;
  const int fr = lane & 15, kq = lane >> 4;
  f32x4 acc[2][2];
#pragma unroll
  for (int i = 0; i < 2; i++)
#pragma unroll
    for (int j = 0; j < 2; j++) acc[i][j] = (f32x4)0.0f;
#pragma unroll
  for (int kk = 0; kk < 2; ++kk) {
    bf16x8 af[2], bfr[2];
#pragma unroll
    for (int i = 0; i < 2; i++) {
      int row = gr + i * 16 + fr;
      af[i] = *(const bf16x8*)(Kt + sw_off(row, kk * 4 + kq));
    }
#pragma unroll
    for (int j = 0; j < 2; j++) {
      int row = gc + j * 16 + fr;
      bfr[j] = *(const bf16x8*)(Vt + sw_off(row, kk * 4 + kq));
    }
#pragma unroll
    for (int i = 0; i < 2; i++)
#pragma unroll
      for (int j = 0; j < 2; j++)
        acc[i][j] = MFMA_BF16(af[i], bfr[j], acc[i][j], 0, 0, 0);
  }
  const int rg = kq * 4;
  __bf16* Gb = G + (size_t)bid * 4096;
#pragma unroll
  for (int i = 0; i < 2; i++)
#pragma unroll
    for (int j = 0; j < 2; j++)
#pragma unroll
      for (int r = 0; r < 4; r++)
        Gb[(gr + i * 16 + rg + r) * 64 + gc + j * 16 + fr] = (__bf16)acc[i][j][r];
}

// ---------------- stage B: prefix over chunks ----------------
__global__ __launch_bounds__(256) void prefix_scan(const __bf16* __restrict__ G,
                                                   const float* __restrict__ sigma0,
                                                   __bf16* __restrict__ S,
                                                   float* __restrict__ sigma_out,
                                                   const float* __restrict__ eta) {
  const int blk = blockIdx.x;       // 0..255
  const int bh = blk >> 2;
  const int dq = blk & 3;
  const int tid = threadIdx.x;
  const int d = dq * 16 + (tid >> 4);
  const int e0 = (tid & 15) * 4;
  const float eta_s = eta[0];
  const size_t base_de = (size_t)d * 64 + e0;
  float acc[4], s0[4];
#pragma unroll
  for (int j = 0; j < 4; j++) {
    acc[j] = 0.0f;
    s0[j] = sigma0[(size_t)bh * 4096 + base_de + j];
  }
  for (int c = 0; c < NC_; ++c) {
    const size_t off = ((size_t)bh * NC_ + c) * 4096 + base_de;
    bf16x4 sv;
#pragma unroll
    for (int j = 0; j < 4; j++) sv[j] = (__bf16)(s0[j] + eta_s * acc[j]);
    *(bf16x4*)(S + off) = sv;
    bf16x4 g = *(const bf16x4*)(G + off);
#pragma unroll
    for (int j = 0; j < 4; j++) acc[j] += (float)g[j];
  }
  float4 v;
  v.x = s0[0] + eta_s * acc[0];
  v.y = s0[1] + eta_s * acc[1];
  v.z = s0[2] + eta_s * acc[2];
  v.w = s0[3] + eta_s * acc[3];
  *reinterpret_cast<float4*>(sigma_out + (size_t)bh * 4096 + base_de) = v;
}

// ---------------- stage C: O = eta*strict_tril(Q K^T) V + Q S_c; swizzled LDS ----------------
__global__ __launch_bounds__(256) void chunk_out(const __bf16* __restrict__ qkv,
                                                 const __bf16* __restrict__ S,
                                                 __bf16* __restrict__ outp,
                                                 const float* __restrict__ eta) {
  __shared__ __bf16 Qs[64 * LDW];  // [t][d] straight, slot-swizzled
  __shared__ __bf16 Ks[64 * LDW];  // [s][d] straight
  __shared__ __bf16 Vt[64 * LDW];  // [e][s] transposed
  __shared__ __bf16 St[64 * LDW];  // [e][d] transposed
  __shared__ __bf16 Ps[64 * LDW];  // [t][s] straight
  const int bid = blockIdx.x;
  const int c = bid & 63, bh = bid >> 6, h = bh & 15, b = bh >> 4;
  const int tid = threadIdx.x;
  const size_t row0 = (size_t)b * T_ + c * 64;
  const float eta_s = eta[0];
#pragma unroll
  for (int it = 0; it < 2; ++it) {
    int task = tid + it * 256;
    int t = task >> 3, d0 = (task & 7) * 8;
    const size_t rb = (row0 + t) * N3_;
    const int ds = d0 >> 3, ts = t >> 3, tl = t & 7;
    *(u16x8*)(Qs + sw_off(t, ds)) = *(const u16x8*)(qkv + rb + h * 64 + d0);
    *(u16x8*)(Ks + sw_off(t, ds)) = *(const u16x8*)(qkv + rb + C_ + h * 64 + d0);
    u16x8 vv = *(const u16x8*)(qkv + rb + 2 * C_ + h * 64 + d0);
    u16x8 sv = *(const u16x8*)(S + (size_t)bid * 4096 + t * 64 + d0);  // t = S row d here
#pragma unroll
    for (int j = 0; j < 8; j++) {
      int e = d0 + j;
      ((unsigned short*)Vt)[sw_off(e, ts) + tl] = vv[j];
      ((unsigned short*)St)[sw_off(e, ts) + tl] = sv[j];
    }
  }
  __syncthreads();
  const int lane = tid & 63, wave = tid >> 6;
  const int qr = (wave >> 1) * 32, qc = (wave & 1) * 32;
  const int fr = lane & 15, kq = lane >> 4, rg = (lane >> 4) * 4;
  // phase 1: P = Q K^T, strict lower mask, *eta -> Ps
  {
    f32x4 pacc[2][2];
#pragma unroll
    for (int i = 0; i < 2; i++)
#pragma unroll
      for (int j = 0; j < 2; j++) pacc[i][j] = (f32x4)0.0f;
#pragma unroll
    for (int kk = 0; kk < 2; ++kk) {
      bf16x8 af[2], bfr[2];
#pragma unroll
      for (int i = 0; i < 2; i++) {
        int row = qr + i * 16 + fr;
        af[i] = *(const bf16x8*)(Qs + sw_off(row, kk * 4 + kq));
      }
#pragma unroll
      for (int j = 0; j < 2; j++) {
        int row = qc + j * 16 + fr;
        bfr[j] = *(const bf16x8*)(Ks + sw_off(row, kk * 4 + kq));
      }
#pragma unroll
      for (int i = 0; i < 2; i++)
#pragma unroll
        for (int j = 0; j < 2; j++)
          pacc[i][j] = MFMA_BF16(af[i], bfr[j], pacc[i][j], 0, 0, 0);
    }
#pragma unroll
    for (int i = 0; i < 2; i++)
#pragma unroll
      for (int j = 0; j < 2; j++)
#pragma unroll
        for (int r = 0; r < 4; r++) {
          int trow = qr + i * 16 + rg + r;
          int scol = qc + j * 16 + fr;
          float v = (scol < trow) ? eta_s * pacc[i][j][r] : 0.0f;
          Ps[sw_off(trow, scol >> 3) + (scol & 7)] = (__bf16)v;
        }
  }
  __syncthreads();
  // phase 2: O = Ps * V + Q * S
  {
    f32x4 oacc[2][2];
#pragma unroll
    for (int i = 0; i < 2; i++)
#pragma unroll
      for (int j = 0; j < 2; j++) oacc[i][j] = (f32x4)0.0f;
#pragma unroll
    for (int kk = 0; kk < 2; ++kk) {
      bf16x8 pa[2], vb[2], qa[2], sb[2];
#pragma unroll
      for (int i = 0; i < 2; i++) {
        int row = qr + i * 16 + fr;
        pa[i] = *(const bf16x8*)(Ps + sw_off(row, kk * 4 + kq));
        qa[i] = *(const bf16x8*)(Qs + sw_off(row, kk * 4 + kq));
      }
#pragma unroll
      for (int j = 0; j < 2; j++) {
        int row = qc + j * 16 + fr;
        vb[j] = *(const bf16x8*)(Vt + sw_off(row, kk * 4 + kq));
        sb[j] = *(const bf16x8*)(St + sw_off(row, kk * 4 + kq));
      }
#pragma unroll
      for (int i = 0; i < 2; i++)
#pragma unroll
        for (int j = 0; j < 2; j++) {
          oacc[i][j] = MFMA_BF16(pa[i], vb[j], oacc[i][j], 0, 0, 0);
          oacc[i][j] = MFMA_BF16(qa[i], sb[j], oacc[i][j], 0, 0, 0);
        }
    }
#pragma unroll
    for (int i = 0; i < 2; i++)
#pragma unroll
      for (int j = 0; j < 2; j++)
#pragma unroll
        for (int r = 0; r < 4; r++) {
          size_t row = row0 + qr + i * 16 + rg + r;
          int col = h * 64 + qc + j * 16 + fr;
          outp[row * C_ + col] = (__bf16)oacc[i][j][r];
        }
  }
}

extern "C" void kernel_launch(void* const* d_in, const int* in_sizes, int n_in,
                              void* d_out, int out_size, void* d_ws, size_t ws_size,
                              hipStream_t stream) {
  const float* x      = (const float*)d_in[0];
  const float* sigma0 = (const float*)d_in[1];
  const float* w_qkv  = (const float*)d_in[2];
  const float* w_proj = (const float*)d_in[3];
  const float* eta    = (const float*)d_in[4];
  float* out       = (float*)d_out;
  float* sigma_out = out + (size_t)M_ * C_;

  char* ws = (char*)d_ws;
  __bf16* xbf     = (__bf16*)(ws);               // 32 MB (reused as out_pre)
  __bf16* wqkvbf  = (__bf16*)(ws + 33554432);
  __bf16* wprojbf = (__bf16*)(ws + 39845888);
  __bf16* qkvbf   = (__bf16*)(ws + 41943040);    // 96 MB
  __bf16* Gws     = (__bf16*)(ws + 142606336);   // 32 MB
  __bf16* Sws     = (__bf16*)(ws + 176160768);   // 32 MB
  float2* tab     = (float2*)(ws + 176160768);   // 1 MB, dead before prefix_scan writes S

  rope_tab<<<512, 256, 0, stream>>>(tab);
  cvt_f32_bf16<<<16384, 256, 0, stream>>>(x, xbf, 4194304);
  cvt_f32_bf16<<<3072, 256, 0, stream>>>(w_qkv, wqkvbf, 786432);
  cvt_f32_bf16<<<1024, 256, 0, stream>>>(w_proj, wprojbf, 262144);
  gemm_8ph<1, 12><<<768, 512, 0, stream>>>(xbf, wqkvbf, (void*)qkvbf, tab, N3_);
  chunk_kv<<<4096, 256, 0, stream>>>(qkvbf, Gws);
  prefix_scan<<<256, 256, 0, stream>>>(Gws, sigma0, Sws, sigma_out, eta);
  chunk_out<<<4096, 256, 0, stream>>>(qkvbf, Sws, xbf, eta);
  gemm_8ph<2, 4><<<256, 512, 0, stream>>>(xbf, wprojbf, (void*)out, nullptr, C_);
}

// Round 25
// 253.377 us; speedup vs baseline: 1.5175x; 1.0379x over previous
//
#include <hip/hip_runtime.h>
#include <hip/hip_bf16.h>
#include <cstdint>
#include <cstddef>

#define B_   4
#define T_   4096
#define C_   1024
#define H_   16
#define NC_  64
#define M_   (B_*T_)     // 16384 rows
#define N3_  (3*C_)      // 3072
#define NTK  16          // K=1024 / BK=64

typedef __attribute__((ext_vector_type(4))) float  f32x4;
typedef __attribute__((ext_vector_type(8))) __bf16 bf16x8;
typedef __attribute__((ext_vector_type(4))) __bf16 bf16x4;
typedef __attribute__((ext_vector_type(8))) unsigned short u16x8;

__device__ __forceinline__ void glds16(void* lds, const void* g) {
  __builtin_amdgcn_global_load_lds((const __attribute__((address_space(1))) void*)g,
                                   (__attribute__((address_space(3))) void*)lds,
                                   16, 0, 0);
}
#define MFMA_BF16 __builtin_amdgcn_mfma_f32_16x16x32_bf16

// LDS slot swizzle for 64x64 tiles stored in [64][LDW=72] (8 data slots of 8 elems + pad):
// physical slot = logical slot XOR (row>>3 & 7). Kills the 16-way transposed-store conflicts.
#define LDW 72
__device__ __forceinline__ int sw_off(int row, int s) {
  return row * LDW + ((s ^ ((row >> 3) & 7)) << 3);
}

// ---------------- fused prep: cvt x, cvt w_qkv, cvt w_proj, rope table ----------------
// blocks [0,16384): x (4194304 float4s); [16384,19456): w_qkv (786432);
// [19456,20480): w_proj (262144); [20480,20992): rope tab (131072 entries).
__global__ __launch_bounds__(256) void prep(const float* __restrict__ x,
                                            const float* __restrict__ w_qkv,
                                            const float* __restrict__ w_proj,
                                            __bf16* __restrict__ xbf,
                                            __bf16* __restrict__ wqkvbf,
                                            __bf16* __restrict__ wprojbf,
                                            float2* __restrict__ tab) {
  const int blk = blockIdx.x;
  if (blk < 20480) {
    const float* in;
    __bf16* out;
    int i;
    if (blk < 16384)      { in = x;      out = xbf;     i = blk * 256 + threadIdx.x; }
    else if (blk < 19456) { in = w_qkv;  out = wqkvbf;  i = (blk - 16384) * 256 + threadIdx.x; }
    else                  { in = w_proj; out = wprojbf; i = (blk - 19456) * 256 + threadIdx.x; }
    float4 v = reinterpret_cast<const float4*>(in)[i];
    bf16x4 o;
    o[0] = (__bf16)v.x; o[1] = (__bf16)v.y; o[2] = (__bf16)v.z; o[3] = (__bf16)v.w;
    reinterpret_cast<bf16x4*>(out)[i] = o;
  } else {
    int gid = (blk - 20480) * 256 + threadIdx.x;  // 131072 entries
    int t = gid >> 5, dp = gid & 31;
    float invf = exp2f(-(float)dp * (13.287712379549449f / 32.0f));
    float ang = (float)t * invf;
    float s, c;
    sincosf(ang, &s, &c);
    tab[gid] = make_float2(c, s);
  }
}

// ============ 256x256 GEMM, BK=64, 8-phase, deep prefetch, XCD swizzle (r16) ============
template<int FUSE, int NBN>
__global__ __launch_bounds__(512) void gemm_8ph(const __bf16* __restrict__ A,
                                                const __bf16* __restrict__ Bt,
                                                void* __restrict__ Cout,
                                                const float2* __restrict__ tab,
                                                int N) {
  __shared__ __bf16 sA[2][2][128 * 64];   // [dbuf][half][row 128][k 64], 16KB each
  __shared__ __bf16 sB[2][2][128 * 64];
  const int tid  = threadIdx.x;
  const int lane = tid & 63;
  const int wave = tid >> 6;
  const int wm = wave >> 2, wn = wave & 3;
  const int nwg = NBN * 64, cpx = nwg / 8;
  const int wgid = (int)blockIdx.x;
  const int swzid = (wgid % 8) * cpx + wgid / 8;
  const int bn = swzid % NBN, bm = swzid / NBN;
  const int fr = lane & 15, kq = lane >> 4;
  const int fr7 = fr & 7;
  const int K = C_;

  const int r_loc = tid >> 3;
  const int sslot = (tid & 7) ^ (r_loc & 7);
  const __bf16* Ag = A  + (size_t)(bm * 256 + r_loc) * K + sslot * 8;
  const __bf16* Bg = Bt + (size_t)(bn * 256 + r_loc) * K + sslot * 8;
  const __bf16* AgH[2] = { Ag, Ag + (size_t)128 * K };
  const __bf16* BgH[2] = { Bg, Bg + (size_t)128 * K };

  f32x4 acc[8][4];
#pragma unroll
  for (int i = 0; i < 8; i++)
#pragma unroll
    for (int j = 0; j < 4; j++) acc[i][j] = (f32x4)0.0f;

#pragma unroll
  for (int h = 0; h < 2; ++h) {
    glds16((char*)sA[0][h] +    0 + tid * 16, AgH[h]);
    glds16((char*)sA[0][h] + 8192 + tid * 16, AgH[h] + (size_t)64 * K);
    glds16((char*)sB[0][h] +    0 + tid * 16, BgH[h]);
    glds16((char*)sB[0][h] + 8192 + tid * 16, BgH[h] + (size_t)64 * K);
  }

  bf16x8 af[4][2], bfr[4][2];
  const int bloc = (wn & 1) * 64;

  for (int t = 0; t < NTK; ++t) {
    const int d = t & 1, nb = d ^ 1;
    const bool dostage = (t + 1 < NTK);
    const int kb1 = (t + 1) * 64;
    const char* Abh = (const char*)sA[d][wm];
    const char* Bbh = (const char*)sB[d][wn >> 1];

    if (dostage) {
      glds16((char*)sA[nb][0] +    0 + tid * 16, AgH[0] + kb1);
      glds16((char*)sA[nb][0] + 8192 + tid * 16, AgH[0] + (size_t)64 * K + kb1);
      glds16((char*)sA[nb][1] +    0 + tid * 16, AgH[1] + kb1);
      glds16((char*)sA[nb][1] + 8192 + tid * 16, AgH[1] + (size_t)64 * K + kb1);
      asm volatile("s_waitcnt vmcnt(4)" ::: "memory");
    } else {
      asm volatile("s_waitcnt vmcnt(0)" ::: "memory");
    }
    __builtin_amdgcn_sched_barrier(0);
    __builtin_amdgcn_s_barrier();
#pragma unroll
    for (int i = 0; i < 4; ++i)
#pragma unroll
      for (int kk = 0; kk < 2; ++kk)
        af[i][kk] = *(const bf16x8*)(Abh + (i * 16 + fr) * 128 + (((kk << 2) | kq) ^ fr7) * 16);
#pragma unroll
    for (int j = 0; j < 2; ++j)
#pragma unroll
      for (int kk = 0; kk < 2; ++kk)
        bfr[j][kk] = *(const bf16x8*)(Bbh + (bloc + j * 16 + fr) * 128 + (((kk << 2) | kq) ^ fr7) * 16);
    asm volatile("s_waitcnt lgkmcnt(0)" ::: "memory");
    __builtin_amdgcn_sched_barrier(0);
    __builtin_amdgcn_s_setprio(1);
#pragma unroll
    for (int i = 0; i < 4; ++i)
#pragma unroll
      for (int j = 0; j < 2; ++j) {
        acc[i][j] = MFMA_BF16(af[i][0], bfr[j][0], acc[i][j], 0, 0, 0);
        acc[i][j] = MFMA_BF16(af[i][1], bfr[j][1], acc[i][j], 0, 0, 0);
      }
    __builtin_amdgcn_s_setprio(0);
    __builtin_amdgcn_s_barrier();

#pragma unroll
    for (int j = 0; j < 2; ++j)
#pragma unroll
      for (int kk = 0; kk < 2; ++kk)
        bfr[j + 2][kk] = *(const bf16x8*)(Bbh + (bloc + (j + 2) * 16 + fr) * 128 + (((kk << 2) | kq) ^ fr7) * 16);
    if (dostage) {
      glds16((char*)sB[nb][0] +    0 + tid * 16, BgH[0] + kb1);
      glds16((char*)sB[nb][0] + 8192 + tid * 16, BgH[0] + (size_t)64 * K + kb1);
      glds16((char*)sB[nb][1] +    0 + tid * 16, BgH[1] + kb1);
      glds16((char*)sB[nb][1] + 8192 + tid * 16, BgH[1] + (size_t)64 * K + kb1);
    }
    __builtin_amdgcn_s_barrier();
    asm volatile("s_waitcnt lgkmcnt(0)" ::: "memory");
    __builtin_amdgcn_sched_barrier(0);
    __builtin_amdgcn_s_setprio(1);
#pragma unroll
    for (int i = 0; i < 4; ++i)
#pragma unroll
      for (int j = 0; j < 2; ++j) {
        acc[i][j + 2] = MFMA_BF16(af[i][0], bfr[j + 2][0], acc[i][j + 2], 0, 0, 0);
        acc[i][j + 2] = MFMA_BF16(af[i][1], bfr[j + 2][1], acc[i][j + 2], 0, 0, 0);
      }
    __builtin_amdgcn_s_setprio(0);
    __builtin_amdgcn_s_barrier();

#pragma unroll
    for (int i = 0; i < 4; ++i)
#pragma unroll
      for (int kk = 0; kk < 2; ++kk)
        af[i][kk] = *(const bf16x8*)(Abh + (64 + i * 16 + fr) * 128 + (((kk << 2) | kq) ^ fr7) * 16);
    asm volatile("s_waitcnt lgkmcnt(0)" ::: "memory");
    __builtin_amdgcn_sched_barrier(0);
    __builtin_amdgcn_s_setprio(1);
#pragma unroll
    for (int i = 0; i < 4; ++i)
#pragma unroll
      for (int j = 0; j < 2; ++j) {
        acc[i + 4][j] = MFMA_BF16(af[i][0], bfr[j][0], acc[i + 4][j], 0, 0, 0);
        acc[i + 4][j] = MFMA_BF16(af[i][1], bfr[j][1], acc[i + 4][j], 0, 0, 0);
      }
    __builtin_amdgcn_s_setprio(0);

    __builtin_amdgcn_s_setprio(1);
#pragma unroll
    for (int i = 0; i < 4; ++i)
#pragma unroll
      for (int j = 0; j < 2; ++j) {
        acc[i + 4][j + 2] = MFMA_BF16(af[i][0], bfr[j + 2][0], acc[i + 4][j + 2], 0, 0, 0);
        acc[i + 4][j + 2] = MFMA_BF16(af[i][1], bfr[j + 2][1], acc[i + 4][j + 2], 0, 0, 0);
      }
    __builtin_amdgcn_s_setprio(0);
    __builtin_amdgcn_s_barrier();
  }

  const int rg4 = kq * 4;
  const int cb = bn * 256 + wn * 64;
  if (FUSE == 1 && bn < 8) {
#pragma unroll
    for (int i = 0; i < 8; ++i)
#pragma unroll
      for (int r = 0; r < 4; ++r) {
        size_t row = (size_t)bm * 256 + wm * 128 + i * 16 + rg4 + r;
        int tt = (int)(row & (T_ - 1));
#pragma unroll
        for (int j = 0; j < 2; ++j) {
          int dp = j * 16 + fr;
          float2 cs = tab[tt * 32 + dp];
          float x1 = acc[i][j][r], x2 = acc[i][j + 2][r];
          float o1 = fmaxf(x1 * cs.x - x2 * cs.y, 0.0f);
          float o2 = fmaxf(x2 * cs.x + x1 * cs.y, 0.0f);
          ((__bf16*)Cout)[row * N + cb + j * 16 + fr]      = (__bf16)o1;
          ((__bf16*)Cout)[row * N + cb + j * 16 + fr + 32] = (__bf16)o2;
        }
      }
  } else {
#pragma unroll
    for (int i = 0; i < 8; ++i)
#pragma unroll
      for (int j = 0; j < 4; ++j) {
        size_t row = (size_t)bm * 256 + wm * 128 + i * 16 + rg4;
        size_t col = (size_t)cb + j * 16 + fr;
#pragma unroll
        for (int r = 0; r < 4; ++r) {
          if (FUSE == 2) ((float*)Cout)[(row + r) * N + col]  = acc[i][j][r];
          else           ((__bf16*)Cout)[(row + r) * N + col] = (__bf16)acc[i][j][r];
        }
      }
  }
}

// ---------------- stage A: G_c = K_c^T V_c per (b,h,chunk); swizzled LDS ----------------
__global__ __launch_bounds__(256) void chunk_kv(const __bf16* __restrict__ qkv,
                                                __bf16* __restrict__ G) {
  __shared__ __bf16 Kt[64 * LDW];  // Kt[d][t], slot-swizzled
  __shared__ __bf16 Vt[64 * LDW];  // Vt[e][t], slot-swizzled
  const int bid = blockIdx.x;
  const int c = bid & (NC_ - 1);
  const int bh = bid >> 6;
  const int h = bh & (H_ - 1);
  const int b = bh >> 4;
  const int tid = threadIdx.x;
  const size_t row0 = (size_t)b * T_ + c * 64;
  const int kcol = C_ + h * 64;
  const int vcol = 2 * C_ + h * 64;
#pragma unroll
  for (int it = 0; it < 2; ++it) {
    int task = tid + it * 256;
    int t = task >> 3;
    int d0 = (task & 7) * 8;
    const size_t rb = (row0 + t) * N3_;
    u16x8 kv = *(const u16x8*)(qkv + rb + kcol + d0);
    u16x8 vv = *(const u16x8*)(qkv + rb + vcol + d0);
    const int ts = t >> 3, tl = t & 7;
#pragma unroll
    for (int j = 0; j < 8; j++) {
      int d = d0 + j;
      ((unsigned short*)Kt)[sw_off(d, ts) + tl] = kv[j];
      ((unsigned short*)Vt)[sw_off(d, ts) + tl] = vv[j];
    }
  }
  __syncthreads();
  const int lane = tid & 63, wave = tid >> 6;
  const int gr = (wave >> 1) * 32, gc = (wave & 1) * 32;
  const int fr = lane & 15, kq = lane >> 4;
  f32x4 acc[2][2];
#pragma unroll
  for (int i = 0; i < 2; i++)
#pragma unroll
    for (int j = 0; j < 2; j++) acc[i][j] = (f32x4)0.0f;
#pragma unroll
  for (int kk = 0; kk < 2; ++kk) {
    bf16x8 af[2], bfr[2];
#pragma unroll
    for (int i = 0; i < 2; i++) {
      int row = gr + i * 16 + fr;
      af[i] = *(const bf16x8*)(Kt + sw_off(row, kk * 4 + kq));
    }
#pragma unroll
    for (int j = 0; j < 2; j++) {
      int row = gc + j * 16 + fr;
      bfr[j] = *(const bf16x8*)(Vt + sw_off(row, kk * 4 + kq));
    }
#pragma unroll
    for (int i = 0; i < 2; i++)
#pragma unroll
      for (int j = 0; j < 2; j++)
        acc[i][j] = MFMA_BF16(af[i], bfr[j], acc[i][j], 0, 0, 0);
  }
  const int rg = kq * 4;
  __bf16* Gb = G + (size_t)bid * 4096;
#pragma unroll
  for (int i = 0; i < 2; i++)
#pragma unroll
    for (int j = 0; j < 2; j++)
#pragma unroll
      for (int r = 0; r < 4; r++)
        Gb[(gr + i * 16 + rg + r) * 64 + gc + j * 16 + fr] = (__bf16)acc[i][j][r];
}

// ---------------- stage B: prefix over chunks ----------------
__global__ __launch_bounds__(256) void prefix_scan(const __bf16* __restrict__ G,
                                                   const float* __restrict__ sigma0,
                                                   __bf16* __restrict__ S,
                                                   float* __restrict__ sigma_out,
                                                   const float* __restrict__ eta) {
  const int blk = blockIdx.x;       // 0..255
  const int bh = blk >> 2;
  const int dq = blk & 3;
  const int tid = threadIdx.x;
  const int d = dq * 16 + (tid >> 4);
  const int e0 = (tid & 15) * 4;
  const float eta_s = eta[0];
  const size_t base_de = (size_t)d * 64 + e0;
  float acc[4], s0[4];
#pragma unroll
  for (int j = 0; j < 4; j++) {
    acc[j] = 0.0f;
    s0[j] = sigma0[(size_t)bh * 4096 + base_de + j];
  }
  for (int c = 0; c < NC_; ++c) {
    const size_t off = ((size_t)bh * NC_ + c) * 4096 + base_de;
    bf16x4 sv;
#pragma unroll
    for (int j = 0; j < 4; j++) sv[j] = (__bf16)(s0[j] + eta_s * acc[j]);
    *(bf16x4*)(S + off) = sv;
    bf16x4 g = *(const bf16x4*)(G + off);
#pragma unroll
    for (int j = 0; j < 4; j++) acc[j] += (float)g[j];
  }
  float4 v;
  v.x = s0[0] + eta_s * acc[0];
  v.y = s0[1] + eta_s * acc[1];
  v.z = s0[2] + eta_s * acc[2];
  v.w = s0[3] + eta_s * acc[3];
  *reinterpret_cast<float4*>(sigma_out + (size_t)bh * 4096 + base_de) = v;
}

// ---------------- stage C: O = eta*strict_tril(Q K^T) V + Q S_c; swizzled LDS ----------------
__global__ __launch_bounds__(256) void chunk_out(const __bf16* __restrict__ qkv,
                                                 const __bf16* __restrict__ S,
                                                 __bf16* __restrict__ outp,
                                                 const float* __restrict__ eta) {
  __shared__ __bf16 Qs[64 * LDW];  // [t][d] straight, slot-swizzled
  __shared__ __bf16 Ks[64 * LDW];  // [s][d] straight
  __shared__ __bf16 Vt[64 * LDW];  // [e][s] transposed
  __shared__ __bf16 St[64 * LDW];  // [e][d] transposed
  __shared__ __bf16 Ps[64 * LDW];  // [t][s] straight
  const int bid = blockIdx.x;
  const int c = bid & 63, bh = bid >> 6, h = bh & 15, b = bh >> 4;
  const int tid = threadIdx.x;
  const size_t row0 = (size_t)b * T_ + c * 64;
  const float eta_s = eta[0];
#pragma unroll
  for (int it = 0; it < 2; ++it) {
    int task = tid + it * 256;
    int t = task >> 3, d0 = (task & 7) * 8;
    const size_t rb = (row0 + t) * N3_;
    const int ds = d0 >> 3, ts = t >> 3, tl = t & 7;
    *(u16x8*)(Qs + sw_off(t, ds)) = *(const u16x8*)(qkv + rb + h * 64 + d0);
    *(u16x8*)(Ks + sw_off(t, ds)) = *(const u16x8*)(qkv + rb + C_ + h * 64 + d0);
    u16x8 vv = *(const u16x8*)(qkv + rb + 2 * C_ + h * 64 + d0);
    u16x8 sv = *(const u16x8*)(S + (size_t)bid * 4096 + t * 64 + d0);  // t = S row d here
#pragma unroll
    for (int j = 0; j < 8; j++) {
      int e = d0 + j;
      ((unsigned short*)Vt)[sw_off(e, ts) + tl] = vv[j];
      ((unsigned short*)St)[sw_off(e, ts) + tl] = sv[j];
    }
  }
  __syncthreads();
  const int lane = tid & 63, wave = tid >> 6;
  const int qr = (wave >> 1) * 32, qc = (wave & 1) * 32;
  const int fr = lane & 15, kq = lane >> 4, rg = (lane >> 4) * 4;
  // phase 1: P = Q K^T, strict lower mask, *eta -> Ps
  {
    f32x4 pacc[2][2];
#pragma unroll
    for (int i = 0; i < 2; i++)
#pragma unroll
      for (int j = 0; j < 2; j++) pacc[i][j] = (f32x4)0.0f;
#pragma unroll
    for (int kk = 0; kk < 2; ++kk) {
      bf16x8 af[2], bfr[2];
#pragma unroll
      for (int i = 0; i < 2; i++) {
        int row = qr + i * 16 + fr;
        af[i] = *(const bf16x8*)(Qs + sw_off(row, kk * 4 + kq));
      }
#pragma unroll
      for (int j = 0; j < 2; j++) {
        int row = qc + j * 16 + fr;
        bfr[j] = *(const bf16x8*)(Ks + sw_off(row, kk * 4 + kq));
      }
#pragma unroll
      for (int i = 0; i < 2; i++)
#pragma unroll
        for (int j = 0; j < 2; j++)
          pacc[i][j] = MFMA_BF16(af[i], bfr[j], pacc[i][j], 0, 0, 0);
    }
#pragma unroll
    for (int i = 0; i < 2; i++)
#pragma unroll
      for (int j = 0; j < 2; j++)
#pragma unroll
        for (int r = 0; r < 4; r++) {
          int trow = qr + i * 16 + rg + r;
          int scol = qc + j * 16 + fr;
          float v = (scol < trow) ? eta_s * pacc[i][j][r] : 0.0f;
          Ps[sw_off(trow, scol >> 3) + (scol & 7)] = (__bf16)v;
        }
  }
  __syncthreads();
  // phase 2: O = Ps * V + Q * S
  {
    f32x4 oacc[2][2];
#pragma unroll
    for (int i = 0; i < 2; i++)
#pragma unroll
      for (int j = 0; j < 2; j++) oacc[i][j] = (f32x4)0.0f;
#pragma unroll
    for (int kk = 0; kk < 2; ++kk) {
      bf16x8 pa[2], vb[2], qa[2], sb[2];
#pragma unroll
      for (int i = 0; i < 2; i++) {
        int row = qr + i * 16 + fr;
        pa[i] = *(const bf16x8*)(Ps + sw_off(row, kk * 4 + kq));
        qa[i] = *(const bf16x8*)(Qs + sw_off(row, kk * 4 + kq));
      }
#pragma unroll
      for (int j = 0; j < 2; j++) {
        int row = qc + j * 16 + fr;
        vb[j] = *(const bf16x8*)(Vt + sw_off(row, kk * 4 + kq));
        sb[j] = *(const bf16x8*)(St + sw_off(row, kk * 4 + kq));
      }
#pragma unroll
      for (int i = 0; i < 2; i++)
#pragma unroll
        for (int j = 0; j < 2; j++) {
          oacc[i][j] = MFMA_BF16(pa[i], vb[j], oacc[i][j], 0, 0, 0);
          oacc[i][j] = MFMA_BF16(qa[i], sb[j], oacc[i][j], 0, 0, 0);
        }
    }
#pragma unroll
    for (int i = 0; i < 2; i++)
#pragma unroll
      for (int j = 0; j < 2; j++)
#pragma unroll
        for (int r = 0; r < 4; r++) {
          size_t row = row0 + qr + i * 16 + rg + r;
          int col = h * 64 + qc + j * 16 + fr;
          outp[row * C_ + col] = (__bf16)oacc[i][j][r];
        }
  }
}

extern "C" void kernel_launch(void* const* d_in, const int* in_sizes, int n_in,
                              void* d_out, int out_size, void* d_ws, size_t ws_size,
                              hipStream_t stream) {
  const float* x      = (const float*)d_in[0];
  const float* sigma0 = (const float*)d_in[1];
  const float* w_qkv  = (const float*)d_in[2];
  const float* w_proj = (const float*)d_in[3];
  const float* eta    = (const float*)d_in[4];
  float* out       = (float*)d_out;
  float* sigma_out = out + (size_t)M_ * C_;

  char* ws = (char*)d_ws;
  __bf16* xbf     = (__bf16*)(ws);               // 32 MB (reused as out_pre)
  __bf16* wqkvbf  = (__bf16*)(ws + 33554432);
  __bf16* wprojbf = (__bf16*)(ws + 39845888);
  __bf16* qkvbf   = (__bf16*)(ws + 41943040);    // 96 MB
  __bf16* Gws     = (__bf16*)(ws + 142606336);   // 32 MB
  __bf16* Sws     = (__bf16*)(ws + 176160768);   // 32 MB
  float2* tab     = (float2*)(ws + 176160768);   // 1 MB, dead before prefix_scan writes S

  prep<<<20992, 256, 0, stream>>>(x, w_qkv, w_proj, xbf, wqkvbf, wprojbf, tab);
  gemm_8ph<1, 12><<<768, 512, 0, stream>>>(xbf, wqkvbf, (void*)qkvbf, tab, N3_);
  chunk_kv<<<4096, 256, 0, stream>>>(qkvbf, Gws);
  prefix_scan<<<256, 256, 0, stream>>>(Gws, sigma0, Sws, sigma_out, eta);
  chunk_out<<<4096, 256, 0, stream>>>(qkvbf, Sws, xbf, eta);
  gemm_8ph<2, 4><<<256, 512, 0, stream>>>(xbf, wprojbf, (void*)out, nullptr, C_);
}

// Round 26
// 253.241 us; speedup vs baseline: 1.5183x; 1.0005x over previous
//
#include <hip/hip_runtime.h>
#include <hip/hip_bf16.h>
#include <cstdint>
#include <cstddef>

#define B_   4
#define T_   4096
#define C_   1024
#define H_   16
#define NC_  64
#define M_   (B_*T_)     // 16384 rows
#define N3_  (3*C_)      // 3072
#define NTK  16          // K=1024 / BK=64

typedef __attribute__((ext_vector_type(4))) float  f32x4;
typedef __attribute__((ext_vector_type(8))) __bf16 bf16x8;
typedef __attribute__((ext_vector_type(4))) __bf16 bf16x4;
typedef __attribute__((ext_vector_type(8))) unsigned short u16x8;

__device__ __forceinline__ void glds16(void* lds, const void* g) {
  __builtin_amdgcn_global_load_lds((const __attribute__((address_space(1))) void*)g,
                                   (__attribute__((address_space(3))) void*)lds,
                                   16, 0, 0);
}
#define MFMA_BF16 __builtin_amdgcn_mfma_f32_16x16x32_bf16

// LDS slot swizzle for 64x64 tiles stored in [64][LDW=72] (8 data slots of 8 elems + pad):
// physical slot = logical slot XOR (row>>3 & 7). Kills the 16-way transposed-store conflicts.
#define LDW 72
__device__ __forceinline__ int sw_off(int row, int s) {
  return row * LDW + ((s ^ ((row >> 3) & 7)) << 3);
}

// ---------------- fused prep: cvt x, cvt w_qkv, cvt w_proj, rope table ----------------
// blocks [0,16384): x (4194304 float4s); [16384,19456): w_qkv (786432);
// [19456,20480): w_proj (262144); [20480,20992): rope tab (131072 entries).
__global__ __launch_bounds__(256) void prep(const float* __restrict__ x,
                                            const float* __restrict__ w_qkv,
                                            const float* __restrict__ w_proj,
                                            __bf16* __restrict__ xbf,
                                            __bf16* __restrict__ wqkvbf,
                                            __bf16* __restrict__ wprojbf,
                                            float2* __restrict__ tab) {
  const int blk = blockIdx.x;
  if (blk < 20480) {
    const float* in;
    __bf16* out;
    int i;
    if (blk < 16384)      { in = x;      out = xbf;     i = blk * 256 + threadIdx.x; }
    else if (blk < 19456) { in = w_qkv;  out = wqkvbf;  i = (blk - 16384) * 256 + threadIdx.x; }
    else                  { in = w_proj; out = wprojbf; i = (blk - 19456) * 256 + threadIdx.x; }
    float4 v = reinterpret_cast<const float4*>(in)[i];
    bf16x4 o;
    o[0] = (__bf16)v.x; o[1] = (__bf16)v.y; o[2] = (__bf16)v.z; o[3] = (__bf16)v.w;
    reinterpret_cast<bf16x4*>(out)[i] = o;
  } else {
    int gid = (blk - 20480) * 256 + threadIdx.x;  // 131072 entries
    int t = gid >> 5, dp = gid & 31;
    float invf = exp2f(-(float)dp * (13.287712379549449f / 32.0f));
    float ang = (float)t * invf;
    float s, c;
    sincosf(ang, &s, &c);
    tab[gid] = make_float2(c, s);
  }
}

// ============ 256x256 GEMM, BK=64, 8-phase, deep prefetch, XCD swizzle (r16) ============
template<int FUSE, int NBN>
__global__ __launch_bounds__(512) void gemm_8ph(const __bf16* __restrict__ A,
                                                const __bf16* __restrict__ Bt,
                                                void* __restrict__ Cout,
                                                const float2* __restrict__ tab,
                                                int N) {
  __shared__ __bf16 sA[2][2][128 * 64];   // [dbuf][half][row 128][k 64], 16KB each
  __shared__ __bf16 sB[2][2][128 * 64];
  const int tid  = threadIdx.x;
  const int lane = tid & 63;
  const int wave = tid >> 6;
  const int wm = wave >> 2, wn = wave & 3;
  const int nwg = NBN * 64, cpx = nwg / 8;
  const int wgid = (int)blockIdx.x;
  const int swzid = (wgid % 8) * cpx + wgid / 8;
  const int bn = swzid % NBN, bm = swzid / NBN;
  const int fr = lane & 15, kq = lane >> 4;
  const int fr7 = fr & 7;
  const int K = C_;

  const int r_loc = tid >> 3;
  const int sslot = (tid & 7) ^ (r_loc & 7);
  const __bf16* Ag = A  + (size_t)(bm * 256 + r_loc) * K + sslot * 8;
  const __bf16* Bg = Bt + (size_t)(bn * 256 + r_loc) * K + sslot * 8;
  const __bf16* AgH[2] = { Ag, Ag + (size_t)128 * K };
  const __bf16* BgH[2] = { Bg, Bg + (size_t)128 * K };

  f32x4 acc[8][4];
#pragma unroll
  for (int i = 0; i < 8; i++)
#pragma unroll
    for (int j = 0; j < 4; j++) acc[i][j] = (f32x4)0.0f;

#pragma unroll
  for (int h = 0; h < 2; ++h) {
    glds16((char*)sA[0][h] +    0 + tid * 16, AgH[h]);
    glds16((char*)sA[0][h] + 8192 + tid * 16, AgH[h] + (size_t)64 * K);
    glds16((char*)sB[0][h] +    0 + tid * 16, BgH[h]);
    glds16((char*)sB[0][h] + 8192 + tid * 16, BgH[h] + (size_t)64 * K);
  }

  bf16x8 af[4][2], bfr[4][2];
  const int bloc = (wn & 1) * 64;

  for (int t = 0; t < NTK; ++t) {
    const int d = t & 1, nb = d ^ 1;
    const bool dostage = (t + 1 < NTK);
    const int kb1 = (t + 1) * 64;
    const char* Abh = (const char*)sA[d][wm];
    const char* Bbh = (const char*)sB[d][wn >> 1];

    if (dostage) {
      glds16((char*)sA[nb][0] +    0 + tid * 16, AgH[0] + kb1);
      glds16((char*)sA[nb][0] + 8192 + tid * 16, AgH[0] + (size_t)64 * K + kb1);
      glds16((char*)sA[nb][1] +    0 + tid * 16, AgH[1] + kb1);
      glds16((char*)sA[nb][1] + 8192 + tid * 16, AgH[1] + (size_t)64 * K + kb1);
      asm volatile("s_waitcnt vmcnt(4)" ::: "memory");
    } else {
      asm volatile("s_waitcnt vmcnt(0)" ::: "memory");
    }
    __builtin_amdgcn_sched_barrier(0);
    __builtin_amdgcn_s_barrier();
#pragma unroll
    for (int i = 0; i < 4; ++i)
#pragma unroll
      for (int kk = 0; kk < 2; ++kk)
        af[i][kk] = *(const bf16x8*)(Abh + (i * 16 + fr) * 128 + (((kk << 2) | kq) ^ fr7) * 16);
#pragma unroll
    for (int j = 0; j < 2; ++j)
#pragma unroll
      for (int kk = 0; kk < 2; ++kk)
        bfr[j][kk] = *(const bf16x8*)(Bbh + (bloc + j * 16 + fr) * 128 + (((kk << 2) | kq) ^ fr7) * 16);
    asm volatile("s_waitcnt lgkmcnt(0)" ::: "memory");
    __builtin_amdgcn_sched_barrier(0);
    __builtin_amdgcn_s_setprio(1);
#pragma unroll
    for (int i = 0; i < 4; ++i)
#pragma unroll
      for (int j = 0; j < 2; ++j) {
        acc[i][j] = MFMA_BF16(af[i][0], bfr[j][0], acc[i][j], 0, 0, 0);
        acc[i][j] = MFMA_BF16(af[i][1], bfr[j][1], acc[i][j], 0, 0, 0);
      }
    __builtin_amdgcn_s_setprio(0);
    __builtin_amdgcn_s_barrier();

#pragma unroll
    for (int j = 0; j < 2; ++j)
#pragma unroll
      for (int kk = 0; kk < 2; ++kk)
        bfr[j + 2][kk] = *(const bf16x8*)(Bbh + (bloc + (j + 2) * 16 + fr) * 128 + (((kk << 2) | kq) ^ fr7) * 16);
    if (dostage) {
      glds16((char*)sB[nb][0] +    0 + tid * 16, BgH[0] + kb1);
      glds16((char*)sB[nb][0] + 8192 + tid * 16, BgH[0] + (size_t)64 * K + kb1);
      glds16((char*)sB[nb][1] +    0 + tid * 16, BgH[1] + kb1);
      glds16((char*)sB[nb][1] + 8192 + tid * 16, BgH[1] + (size_t)64 * K + kb1);
    }
    __builtin_amdgcn_s_barrier();
    asm volatile("s_waitcnt lgkmcnt(0)" ::: "memory");
    __builtin_amdgcn_sched_barrier(0);
    __builtin_amdgcn_s_setprio(1);
#pragma unroll
    for (int i = 0; i < 4; ++i)
#pragma unroll
      for (int j = 0; j < 2; ++j) {
        acc[i][j + 2] = MFMA_BF16(af[i][0], bfr[j + 2][0], acc[i][j + 2], 0, 0, 0);
        acc[i][j + 2] = MFMA_BF16(af[i][1], bfr[j + 2][1], acc[i][j + 2], 0, 0, 0);
      }
    __builtin_amdgcn_s_setprio(0);
    __builtin_amdgcn_s_barrier();

#pragma unroll
    for (int i = 0; i < 4; ++i)
#pragma unroll
      for (int kk = 0; kk < 2; ++kk)
        af[i][kk] = *(const bf16x8*)(Abh + (64 + i * 16 + fr) * 128 + (((kk << 2) | kq) ^ fr7) * 16);
    asm volatile("s_waitcnt lgkmcnt(0)" ::: "memory");
    __builtin_amdgcn_sched_barrier(0);
    __builtin_amdgcn_s_setprio(1);
#pragma unroll
    for (int i = 0; i < 4; ++i)
#pragma unroll
      for (int j = 0; j < 2; ++j) {
        acc[i + 4][j] = MFMA_BF16(af[i][0], bfr[j][0], acc[i + 4][j], 0, 0, 0);
        acc[i + 4][j] = MFMA_BF16(af[i][1], bfr[j][1], acc[i + 4][j], 0, 0, 0);
      }
    __builtin_amdgcn_s_setprio(0);

    __builtin_amdgcn_s_setprio(1);
#pragma unroll
    for (int i = 0; i < 4; ++i)
#pragma unroll
      for (int j = 0; j < 2; ++j) {
        acc[i + 4][j + 2] = MFMA_BF16(af[i][0], bfr[j + 2][0], acc[i + 4][j + 2], 0, 0, 0);
        acc[i + 4][j + 2] = MFMA_BF16(af[i][1], bfr[j + 2][1], acc[i + 4][j + 2], 0, 0, 0);
      }
    __builtin_amdgcn_s_setprio(0);
    __builtin_amdgcn_s_barrier();
  }

  const int rg4 = kq * 4;
  const int cb = bn * 256 + wn * 64;
  if (FUSE == 1 && bn < 8) {
#pragma unroll
    for (int i = 0; i < 8; ++i)
#pragma unroll
      for (int r = 0; r < 4; ++r) {
        size_t row = (size_t)bm * 256 + wm * 128 + i * 16 + rg4 + r;
        int tt = (int)(row & (T_ - 1));
#pragma unroll
        for (int j = 0; j < 2; ++j) {
          int dp = j * 16 + fr;
          float2 cs = tab[tt * 32 + dp];
          float x1 = acc[i][j][r], x2 = acc[i][j + 2][r];
          float o1 = fmaxf(x1 * cs.x - x2 * cs.y, 0.0f);
          float o2 = fmaxf(x2 * cs.x + x1 * cs.y, 0.0f);
          ((__bf16*)Cout)[row * N + cb + j * 16 + fr]      = (__bf16)o1;
          ((__bf16*)Cout)[row * N + cb + j * 16 + fr + 32] = (__bf16)o2;
        }
      }
  } else {
#pragma unroll
    for (int i = 0; i < 8; ++i)
#pragma unroll
      for (int j = 0; j < 4; ++j) {
        size_t row = (size_t)bm * 256 + wm * 128 + i * 16 + rg4;
        size_t col = (size_t)cb + j * 16 + fr;
#pragma unroll
        for (int r = 0; r < 4; ++r) {
          if (FUSE == 2) ((float*)Cout)[(row + r) * N + col]  = acc[i][j][r];
          else           ((__bf16*)Cout)[(row + r) * N + col] = (__bf16)acc[i][j][r];
        }
      }
  }
}

// ---------------- stage A: G_c = K_c^T V_c per (b,h,chunk); swizzled LDS ----------------
__global__ __launch_bounds__(256) void chunk_kv(const __bf16* __restrict__ qkv,
                                                __bf16* __restrict__ G) {
  __shared__ __bf16 Kt[64 * LDW];  // Kt[d][t], slot-swizzled
  __shared__ __bf16 Vt[64 * LDW];  // Vt[e][t], slot-swizzled
  const int bid = blockIdx.x;
  const int c = bid & (NC_ - 1);
  const int bh = bid >> 6;
  const int h = bh & (H_ - 1);
  const int b = bh >> 4;
  const int tid = threadIdx.x;
  const size_t row0 = (size_t)b * T_ + c * 64;
  const int kcol = C_ + h * 64;
  const int vcol = 2 * C_ + h * 64;
#pragma unroll
  for (int it = 0; it < 2; ++it) {
    int task = tid + it * 256;
    int t = task >> 3;
    int d0 = (task & 7) * 8;
    const size_t rb = (row0 + t) * N3_;
    u16x8 kv = *(const u16x8*)(qkv + rb + kcol + d0);
    u16x8 vv = *(const u16x8*)(qkv + rb + vcol + d0);
    const int ts = t >> 3, tl = t & 7;
#pragma unroll
    for (int j = 0; j < 8; j++) {
      int d = d0 + j;
      ((unsigned short*)Kt)[sw_off(d, ts) + tl] = kv[j];
      ((unsigned short*)Vt)[sw_off(d, ts) + tl] = vv[j];
    }
  }
  __syncthreads();
  const int lane = tid & 63, wave = tid >> 6;
  const int gr = (wave >> 1) * 32, gc = (wave & 1) * 32;
  const int fr = lane & 15, kq = lane >> 4;
  f32x4 acc[2][2];
#pragma unroll
  for (int i = 0; i < 2; i++)
#pragma unroll
    for (int j = 0; j < 2; j++) acc[i][j] = (f32x4)0.0f;
#pragma unroll
  for (int kk = 0; kk < 2; ++kk) {
    bf16x8 af[2], bfr[2];
#pragma unroll
    for (int i = 0; i < 2; i++) {
      int row = gr + i * 16 + fr;
      af[i] = *(const bf16x8*)(Kt + sw_off(row, kk * 4 + kq));
    }
#pragma unroll
    for (int j = 0; j < 2; j++) {
      int row = gc + j * 16 + fr;
      bfr[j] = *(const bf16x8*)(Vt + sw_off(row, kk * 4 + kq));
    }
#pragma unroll
    for (int i = 0; i < 2; i++)
#pragma unroll
      for (int j = 0; j < 2; j++)
        acc[i][j] = MFMA_BF16(af[i], bfr[j], acc[i][j], 0, 0, 0);
  }
  const int rg = kq * 4;
  __bf16* Gb = G + (size_t)bid * 4096;
#pragma unroll
  for (int i = 0; i < 2; i++)
#pragma unroll
    for (int j = 0; j < 2; j++)
#pragma unroll
      for (int r = 0; r < 4; r++)
        Gb[(gr + i * 16 + rg + r) * 64 + gc + j * 16 + fr] = (__bf16)acc[i][j][r];
}

// ---------------- stage B: prefix over chunks ----------------
__global__ __launch_bounds__(256) void prefix_scan(const __bf16* __restrict__ G,
                                                   const float* __restrict__ sigma0,
                                                   __bf16* __restrict__ S,
                                                   float* __restrict__ sigma_out,
                                                   const float* __restrict__ eta) {
  const int blk = blockIdx.x;       // 0..255
  const int bh = blk >> 2;
  const int dq = blk & 3;
  const int tid = threadIdx.x;
  const int d = dq * 16 + (tid >> 4);
  const int e0 = (tid & 15) * 4;
  const float eta_s = eta[0];
  const size_t base_de = (size_t)d * 64 + e0;
  float acc[4], s0[4];
#pragma unroll
  for (int j = 0; j < 4; j++) {
    acc[j] = 0.0f;
    s0[j] = sigma0[(size_t)bh * 4096 + base_de + j];
  }
  for (int c = 0; c < NC_; ++c) {
    const size_t off = ((size_t)bh * NC_ + c) * 4096 + base_de;
    bf16x4 sv;
#pragma unroll
    for (int j = 0; j < 4; j++) sv[j] = (__bf16)(s0[j] + eta_s * acc[j]);
    *(bf16x4*)(S + off) = sv;
    bf16x4 g = *(const bf16x4*)(G + off);
#pragma unroll
    for (int j = 0; j < 4; j++) acc[j] += (float)g[j];
  }
  float4 v;
  v.x = s0[0] + eta_s * acc[0];
  v.y = s0[1] + eta_s * acc[1];
  v.z = s0[2] + eta_s * acc[2];
  v.w = s0[3] + eta_s * acc[3];
  *reinterpret_cast<float4*>(sigma_out + (size_t)bh * 4096 + base_de) = v;
}

// ---------------- stage C: O = eta*strict_tril(Q K^T) V + Q S_c; swizzled LDS ----------------
__global__ __launch_bounds__(256) void chunk_out(const __bf16* __restrict__ qkv,
                                                 const __bf16* __restrict__ S,
                                                 __bf16* __restrict__ outp,
                                                 const float* __restrict__ eta) {
  __shared__ __bf16 Qs[64 * LDW];  // [t][d] straight, slot-swizzled
  __shared__ __bf16 Ks[64 * LDW];  // [s][d] straight
  __shared__ __bf16 Vt[64 * LDW];  // [e][s] transposed
  __shared__ __bf16 St[64 * LDW];  // [e][d] transposed
  __shared__ __bf16 Ps[64 * LDW];  // [t][s] straight
  const int bid = blockIdx.x;
  const int c = bid & 63, bh = bid >> 6, h = bh & 15, b = bh >> 4;
  const int tid = threadIdx.x;
  const size_t row0 = (size_t)b * T_ + c * 64;
  const float eta_s = eta[0];
#pragma unroll
  for (int it = 0; it < 2; ++it) {
    int task = tid + it * 256;
    int t = task >> 3, d0 = (task & 7) * 8;
    const size_t rb = (row0 + t) * N3_;
    const int ds = d0 >> 3, ts = t >> 3, tl = t & 7;
    *(u16x8*)(Qs + sw_off(t, ds)) = *(const u16x8*)(qkv + rb + h * 64 + d0);
    *(u16x8*)(Ks + sw_off(t, ds)) = *(const u16x8*)(qkv + rb + C_ + h * 64 + d0);
    u16x8 vv = *(const u16x8*)(qkv + rb + 2 * C_ + h * 64 + d0);
    u16x8 sv = *(const u16x8*)(S + (size_t)bid * 4096 + t * 64 + d0);  // t = S row d here
#pragma unroll
    for (int j = 0; j < 8; j++) {
      int e = d0 + j;
      ((unsigned short*)Vt)[sw_off(e, ts) + tl] = vv[j];
      ((unsigned short*)St)[sw_off(e, ts) + tl] = sv[j];
    }
  }
  __syncthreads();
  const int lane = tid & 63, wave = tid >> 6;
  const int qr = (wave >> 1) * 32, qc = (wave & 1) * 32;
  const int fr = lane & 15, kq = lane >> 4, rg = (lane >> 4) * 4;
  // phase 1: P = Q K^T, strict lower mask, *eta -> Ps
  {
    f32x4 pacc[2][2];
#pragma unroll
    for (int i = 0; i < 2; i++)
#pragma unroll
      for (int j = 0; j < 2; j++) pacc[i][j] = (f32x4)0.0f;
#pragma unroll
    for (int kk = 0; kk < 2; ++kk) {
      bf16x8 af[2], bfr[2];
#pragma unroll
      for (int i = 0; i < 2; i++) {
        int row = qr + i * 16 + fr;
        af[i] = *(const bf16x8*)(Qs + sw_off(row, kk * 4 + kq));
      }
#pragma unroll
      for (int j = 0; j < 2; j++) {
        int row = qc + j * 16 + fr;
        bfr[j] = *(const bf16x8*)(Ks + sw_off(row, kk * 4 + kq));
      }
#pragma unroll
      for (int i = 0; i < 2; i++)
#pragma unroll
        for (int j = 0; j < 2; j++)
          pacc[i][j] = MFMA_BF16(af[i], bfr[j], pacc[i][j], 0, 0, 0);
    }
#pragma unroll
    for (int i = 0; i < 2; i++)
#pragma unroll
      for (int j = 0; j < 2; j++)
#pragma unroll
        for (int r = 0; r < 4; r++) {
          int trow = qr + i * 16 + rg + r;
          int scol = qc + j * 16 + fr;
          float v = (scol < trow) ? eta_s * pacc[i][j][r] : 0.0f;
          Ps[sw_off(trow, scol >> 3) + (scol & 7)] = (__bf16)v;
        }
  }
  __syncthreads();
  // phase 2: O = Ps * V + Q * S
  {
    f32x4 oacc[2][2];
#pragma unroll
    for (int i = 0; i < 2; i++)
#pragma unroll
      for (int j = 0; j < 2; j++) oacc[i][j] = (f32x4)0.0f;
#pragma unroll
    for (int kk = 0; kk < 2; ++kk) {
      bf16x8 pa[2], vb[2], qa[2], sb[2];
#pragma unroll
      for (int i = 0; i < 2; i++) {
        int row = qr + i * 16 + fr;
        pa[i] = *(const bf16x8*)(Ps + sw_off(row, kk * 4 + kq));
        qa[i] = *(const bf16x8*)(Qs + sw_off(row, kk * 4 + kq));
      }
#pragma unroll
      for (int j = 0; j < 2; j++) {
        int row = qc + j * 16 + fr;
        vb[j] = *(const bf16x8*)(Vt + sw_off(row, kk * 4 + kq));
        sb[j] = *(const bf16x8*)(St + sw_off(row, kk * 4 + kq));
      }
#pragma unroll
      for (int i = 0; i < 2; i++)
#pragma unroll
        for (int j = 0; j < 2; j++) {
          oacc[i][j] = MFMA_BF16(pa[i], vb[j], oacc[i][j], 0, 0, 0);
          oacc[i][j] = MFMA_BF16(qa[i], sb[j], oacc[i][j], 0, 0, 0);
        }
    }
#pragma unroll
    for (int i = 0; i < 2; i++)
#pragma unroll
      for (int j = 0; j < 2; j++)
#pragma unroll
        for (int r = 0; r < 4; r++) {
          size_t row = row0 + qr + i * 16 + rg + r;
          int col = h * 64 + qc + j * 16 + fr;
          outp[row * C_ + col] = (__bf16)oacc[i][j][r];
        }
  }
}

extern "C" void kernel_launch(void* const* d_in, const int* in_sizes, int n_in,
                              void* d_out, int out_size, void* d_ws, size_t ws_size,
                              hipStream_t stream) {
  const float* x      = (const float*)d_in[0];
  const float* sigma0 = (const float*)d_in[1];
  const float* w_qkv  = (const float*)d_in[2];
  const float* w_proj = (const float*)d_in[3];
  const float* eta    = (const float*)d_in[4];
  float* out       = (float*)d_out;
  float* sigma_out = out + (size_t)M_ * C_;

  char* ws = (char*)d_ws;
  __bf16* xbf     = (__bf16*)(ws);               // 32 MB (reused as out_pre)
  __bf16* wqkvbf  = (__bf16*)(ws + 33554432);
  __bf16* wprojbf = (__bf16*)(ws + 39845888);
  __bf16* qkvbf   = (__bf16*)(ws + 41943040);    // 96 MB
  __bf16* Gws     = (__bf16*)(ws + 142606336);   // 32 MB
  __bf16* Sws     = (__bf16*)(ws + 176160768);   // 32 MB
  float2* tab     = (float2*)(ws + 176160768);   // 1 MB, dead before prefix_scan writes S

  prep<<<20992, 256, 0, stream>>>(x, w_qkv, w_proj, xbf, wqkvbf, wprojbf, tab);
  gemm_8ph<1, 12><<<768, 512, 0, stream>>>(xbf, wqkvbf, (void*)qkvbf, tab, N3_);
  chunk_kv<<<4096, 256, 0, stream>>>(qkvbf, Gws);
  prefix_scan<<<256, 256, 0, stream>>>(Gws, sigma0, Sws, sigma_out, eta);
  chunk_out<<<4096, 256, 0, stream>>>(qkvbf, Sws, xbf, eta);
  gemm_8ph<2, 4><<<256, 512, 0, stream>>>(xbf, wprojbf, (void*)out, nullptr, C_);
}